// Round 1
// baseline (115.372 us; speedup 1.0000x reference)
//
#include <hip/hip_runtime.h>
#include <cfloat>
#include <climits>

#define NTRAIN 50000
#define DIM 64
#define BQ 128
#define NCLS 10
#define KSEL 16
#define TB 16                 // test points per block (2 per wave)
#define GROUPS (BQ / TB)      // 8
#define THREADS 512
#define TROWS 64
#define TPAD 68               // 16B-aligned float4 rows, conflict = structural min

__global__ __launch_bounds__(THREADS) void knn_partial(
    const float* __restrict__ train, const float* __restrict__ xtest,
    float* __restrict__ cand_d, int* __restrict__ cand_i,
    int nslices, int slice_len)
{
    __shared__ float qs[TB * DIM];          // 4 KB
    __shared__ float tile[TROWS * TPAD];    // 17.4 KB

    const int bx   = blockIdx.x;
    const int s    = bx % nslices;          // slice id -> XCD = s%8 (L2 locality)
    const int g    = bx / nslices;          // query group
    const int tid  = threadIdx.x;
    const int w    = tid >> 6;
    const int lane = tid & 63;

    for (int i = tid; i < TB * DIM; i += THREADS)
        qs[i] = xtest[g * TB * DIM + i];
    __syncthreads();

    const int row0 = s * slice_len;
    const int row1 = min(NTRAIN, row0 + slice_len);

    // per-lane top-16 (sorted ascending), static indexing only
    float d0[KSEL], d1[KSEL];
    int   i0[KSEL], i1[KSEL];
#pragma unroll
    for (int j = 0; j < KSEL; ++j) { d0[j] = FLT_MAX; d1[j] = FLT_MAX; i0[j] = INT_MAX; i1[j] = INT_MAX; }

    const float* q0 = &qs[(2 * w)     * DIM];
    const float* q1 = &qs[(2 * w + 1) * DIM];

    for (int base = row0; base < row1; base += TROWS) {
        const int nrows = min(TROWS, row1 - base);
        const int nf4   = nrows * (DIM / 4);
        for (int f = tid; f < nf4; f += THREADS) {
            const int r = f >> 4, c = f & 15;
            const float4 v = *(const float4*)&train[(size_t)(base + r) * DIM + 4 * c];
            *(float4*)&tile[r * TPAD + 4 * c] = v;
        }
        __syncthreads();

        if (lane < nrows) {
            const float* trow = &tile[lane * TPAD];
            double a0 = 0.0, a1 = 0.0;
#pragma unroll
            for (int d4 = 0; d4 < DIM / 4; ++d4) {
                const float4 t  = *(const float4*)&trow[4 * d4];
                const float4 qa = *(const float4*)&q0[4 * d4];
                const float4 qb = *(const float4*)&q1[4 * d4];
                const float s0 = fabsf(t.x - qa.x) + fabsf(t.y - qa.y) +
                                 fabsf(t.z - qa.z) + fabsf(t.w - qa.w);
                const float s1 = fabsf(t.x - qb.x) + fabsf(t.y - qb.y) +
                                 fabsf(t.z - qb.z) + fabsf(t.w - qb.w);
                a0 += (double)s0;
                a1 += (double)s1;
            }
            const float f0 = (float)a0, f1 = (float)a1;
            const int gi = base + lane;
            if (f0 < d0[KSEL - 1]) {
                d0[KSEL - 1] = f0; i0[KSEL - 1] = gi;
#pragma unroll
                for (int j = KSEL - 1; j > 0; --j)
                    if (d0[j] < d0[j - 1]) {
                        float td = d0[j]; d0[j] = d0[j - 1]; d0[j - 1] = td;
                        int   ti = i0[j]; i0[j] = i0[j - 1]; i0[j - 1] = ti;
                    }
            }
            if (f1 < d1[KSEL - 1]) {
                d1[KSEL - 1] = f1; i1[KSEL - 1] = gi;
#pragma unroll
                for (int j = KSEL - 1; j > 0; --j)
                    if (d1[j] < d1[j - 1]) {
                        float td = d1[j]; d1[j] = d1[j - 1]; d1[j - 1] = td;
                        int   ti = i1[j]; i1[j] = i1[j - 1]; i1[j - 1] = ti;
                    }
            }
        }
        __syncthreads();
    }

    // Wave-level exact merge: 64 sorted 16-lists -> slice top-16, per test point.
    // Cursor advance uses a static cndmask chain (no dynamic register indexing).
#pragma unroll
    for (int j = 0; j < 2; ++j) {
        float hd = j ? d1[0] : d0[0];
        int   hi = j ? i1[0] : i0[0];
        int c = 0;
        float od = 0.0f; int oi = 0;
        for (int r = 0; r < KSEL; ++r) {
            float wd = hd; int wi = hi;
#pragma unroll
            for (int sh = 1; sh < 64; sh <<= 1) {
                const float xd = __shfl_xor(wd, sh);
                const int   xi = __shfl_xor(wi, sh);
                if (xd < wd || (xd == wd && xi < wi)) { wd = xd; wi = xi; }
            }
            if (wi == hi) {            // this lane supplied the winner (idx unique)
                ++c;
                float nd = FLT_MAX; int ni = INT_MAX;
#pragma unroll
                for (int q = 1; q < KSEL; ++q)
                    if (c == q) { nd = j ? d1[q] : d0[q]; ni = j ? i1[q] : i0[q]; }
                hd = nd; hi = ni;
            }
            if (lane == r) { od = wd; oi = wi; }
        }
        const int tp = g * TB + 2 * w + j;
        if (lane < KSEL) {
            cand_d[((size_t)tp * nslices + s) * KSEL + lane] = od;
            cand_i[((size_t)tp * nslices + s) * KSEL + lane] = oi;
        }
    }
}

__global__ __launch_bounds__(64) void knn_final(
    const float* __restrict__ cand_d, const int* __restrict__ cand_i,
    const float* __restrict__ ttarget, int* __restrict__ out, int nslices)
{
    const int b     = blockIdx.x;
    const int lane  = threadIdx.x;
    const int ncand = nslices * KSEL;

    float ld[KSEL]; int li[KSEL];
#pragma unroll
    for (int j = 0; j < KSEL; ++j) { ld[j] = FLT_MAX; li[j] = INT_MAX; }

    for (int q = lane; q < ncand; q += 64) {
        const float dv = cand_d[(size_t)b * ncand + q];
        const int   iv = cand_i[(size_t)b * ncand + q];
        if (dv < ld[KSEL - 1] || (dv == ld[KSEL - 1] && iv < li[KSEL - 1])) {
            ld[KSEL - 1] = dv; li[KSEL - 1] = iv;
#pragma unroll
            for (int j = KSEL - 1; j > 0; --j)
                if (ld[j] < ld[j - 1] || (ld[j] == ld[j - 1] && li[j] < li[j - 1])) {
                    float td = ld[j]; ld[j] = ld[j - 1]; ld[j - 1] = td;
                    int   ti = li[j]; li[j] = li[j - 1]; li[j - 1] = ti;
                }
        }
    }

    float hd = ld[0]; int hi = li[0]; int c = 0;
    float v = 0.0f;
    for (int r = 0; r < KSEL; ++r) {
        float wd = hd; int wi = hi;
#pragma unroll
        for (int sh = 1; sh < 64; sh <<= 1) {
            const float xd = __shfl_xor(wd, sh);
            const int   xi = __shfl_xor(wi, sh);
            if (xd < wd || (xd == wd && xi < wi)) { wd = xd; wi = xi; }
        }
        if (wi == hi) {
            ++c;
            float nd = FLT_MAX; int ni = INT_MAX;
#pragma unroll
            for (int q = 1; q < KSEL; ++q)
                if (c == q) { nd = ld[q]; ni = li[q]; }
            hd = nd; hi = ni;
        }
        if (lane < NCLS) v += ttarget[(size_t)wi * NCLS + lane];  // one-hot vote
    }

    float bv = (lane < NCLS) ? v : -1.0f;
    int   bc = lane;
#pragma unroll
    for (int sh = 1; sh < 64; sh <<= 1) {
        const float xv = __shfl_xor(bv, sh);
        const int   xc = __shfl_xor(bc, sh);
        if (xv > bv || (xv == bv && xc < bc)) { bv = xv; bc = xc; }  // tie -> lowest class
    }
    if (lane == 0) out[b] = bc;
}

extern "C" void kernel_launch(void* const* d_in, const int* in_sizes, int n_in,
                              void* d_out, int out_size, void* d_ws, size_t ws_size,
                              hipStream_t stream) {
    const float* train   = (const float*)d_in[0];
    const float* ttarget = (const float*)d_in[1];
    const float* xtest   = (const float*)d_in[2];
    int* out = (int*)d_out;

    int nslices = 32;
    while (nslices > 1 && (size_t)BQ * nslices * KSEL * 8 > ws_size) nslices >>= 1;
    const int slice_len = (NTRAIN + nslices - 1) / nslices;

    float* cand_d = (float*)d_ws;
    int*   cand_i = (int*)((char*)d_ws + (size_t)BQ * nslices * KSEL * sizeof(float));

    hipLaunchKernelGGL(knn_partial, dim3(GROUPS * nslices), dim3(THREADS), 0, stream,
                       train, xtest, cand_d, cand_i, nslices, slice_len);
    hipLaunchKernelGGL(knn_final, dim3(BQ), dim3(64), 0, stream,
                       cand_d, cand_i, ttarget, out, nslices);
}